// Round 13
// baseline (267.192 us; speedup 1.0000x reference)
//
#include <hip/hip_runtime.h>

#define NUM_USER   50000
#define NUM_ITEM   50000
#define NUM_NODES  100000
#define DIM_LATENT 256
#define DIM_ID     64
#define NUM_EDGES  2000000
#define NBUCKET    391        // ceil(100000/256) buckets of 256 nodes
#define BPB        8192       // edges per chunk for counting sort
#define NCHUNK     245        // ceil(NUM_EDGES/BPB)
#define HSTRIDE    392

typedef __attribute__((ext_vector_type(8))) short bf8_t;
typedef __attribute__((ext_vector_type(4))) float f4_t;

static __device__ __forceinline__ float lrelu(float x) {
    return x > 0.0f ? x : 0.01f * x;
}
static __device__ __forceinline__ unsigned short f2bf(float f) {
    unsigned u = __float_as_uint(f);
    u += 0x7fff + ((u >> 16) & 1);
    return (unsigned short)(u >> 16);
}
static __device__ __forceinline__ float bf2f(unsigned short u) {
    return __uint_as_float(((unsigned)u) << 16);
}
static __device__ __forceinline__ float bflo(unsigned u) {
    return __uint_as_float(u << 16);
}
static __device__ __forceinline__ float bfhi(unsigned u) {
    return __uint_as_float(u & 0xffff0000u);
}

// ---------------- normalize rows -> bf16 xn ----------------
__global__ void __launch_bounds__(256, 8) k_xnorm(const float* __restrict__ pref,
                                                  const float* __restrict__ feat,
                                                  unsigned short* __restrict__ xn) {
    const int w = threadIdx.x >> 6;
    const int lane = threadIdx.x & 63;
    const int n = blockIdx.x * 4 + w;
    const float* src = (n < NUM_USER) ? (pref + (size_t)n * DIM_LATENT)
                                      : (feat + (size_t)(n - NUM_USER) * DIM_LATENT);
    float4 v = reinterpret_cast<const float4*>(src)[lane];
    float ss = v.x*v.x + v.y*v.y + v.z*v.z + v.w*v.w;
    #pragma unroll
    for (int off = 32; off >= 1; off >>= 1) ss += __shfl_xor(ss, off);
    float sc = 1.0f / fmaxf(sqrtf(ss), 1e-12f);
    ushort4 p;
    p.x = f2bf(v.x * sc); p.y = f2bf(v.y * sc);
    p.z = f2bf(v.z * sc); p.w = f2bf(v.w * sc);
    *reinterpret_cast<ushort4*>(&xn[(size_t)n * DIM_LATENT + lane * 4]) = p;
}

// ---------------- pass 1: per-chunk bucket histogram (LDS atomics only) ----------------
__global__ void __launch_bounds__(256) k_hist(const int* __restrict__ row,
                                              int* __restrict__ hist) {
    __shared__ int lh[NBUCKET];
    const int g = blockIdx.x, t = threadIdx.x;
    for (int i = t; i < NBUCKET; i += 256) lh[i] = 0;
    __syncthreads();
    const int base = g * BPB;
    for (int i = 0; i < BPB; i += 256) {
        int e = base + i + t;
        if (e < NUM_EDGES) atomicAdd(&lh[row[e] >> 8], 1);
    }
    __syncthreads();
    for (int i = t; i < NBUCKET; i += 256) hist[g * HSTRIDE + i] = lh[i];
}

// ---------------- pass 2a: per-bucket scan over chunks; hist -> exclusive, bcnt ----------------
__global__ void __launch_bounds__(256) k_off1(int* __restrict__ hist,
                                              int* __restrict__ bcnt) {
    __shared__ int wsum[4];
    const int b = blockIdx.x, t = threadIdx.x;
    const int lane = t & 63, w = t >> 6;
    int c = (t < NCHUNK) ? hist[t * HSTRIDE + b] : 0;
    int v = c;
    #pragma unroll
    for (int off = 1; off < 64; off <<= 1) {
        int u = __shfl_up(v, off);
        if (lane >= off) v += u;
    }
    if (lane == 63) wsum[w] = v;
    __syncthreads();
    int add = 0;
    #pragma unroll
    for (int i = 0; i < 4; ++i) if (i < w) add += wsum[i];
    int incl = v + add;
    if (t < NCHUNK) hist[t * HSTRIDE + b] = incl - c;
    if (t == 255) bcnt[b] = incl;
}

// ---------------- pass 2b: exclusive scan over 391 bucket counts -> boff ----------------
__global__ void __launch_bounds__(512) k_bscan(const int* __restrict__ bcnt,
                                               int* __restrict__ boff) {
    __shared__ int wsum[8];
    const int t = threadIdx.x;
    const int lane = t & 63, w = t >> 6;
    int c = (t < NBUCKET) ? bcnt[t] : 0;
    int v = c;
    #pragma unroll
    for (int off = 1; off < 64; off <<= 1) {
        int u = __shfl_up(v, off);
        if (lane >= off) v += u;
    }
    if (lane == 63) wsum[w] = v;
    __syncthreads();
    int add = 0;
    #pragma unroll
    for (int i = 0; i < 8; ++i) if (i < w) add += wsum[i];
    int ex = v + add - c;
    if (t < NBUCKET) boff[t] = ex;
    if (t == NBUCKET - 1) boff[NBUCKET] = ex + c;   // == NUM_EDGES
}

// ---------------- pass 3: scatter packed edges to bucket-contiguous epack ----------------
// pack: (local_node << 24) | col   (col < 2^17)
__global__ void __launch_bounds__(256) k_bin2(const int* __restrict__ row,
                                              const int* __restrict__ col,
                                              const int* __restrict__ hist,
                                              const int* __restrict__ boff,
                                              unsigned* __restrict__ epack) {
    __shared__ int curs[NBUCKET];
    const int g = blockIdx.x, t = threadIdx.x;
    for (int i = t; i < NBUCKET; i += 256) curs[i] = boff[i] + hist[g * HSTRIDE + i];
    __syncthreads();
    const int base = g * BPB;
    for (int i = 0; i < BPB; i += 256) {
        int e = base + i + t;
        if (e < NUM_EDGES) {
            int r = row[e];
            int pos = atomicAdd(&curs[r >> 8], 1);
            epack[pos] = ((unsigned)(r & 255) << 24) | (unsigned)col[e];
        }
    }
}

// ---------------- pass 4: bucket-local exact CSR: offs, cnt, dis, ecol ----------------
__global__ void __launch_bounds__(512) k_csr(const unsigned* __restrict__ epack,
                                             const int* __restrict__ boff,
                                             int* __restrict__ offs,
                                             int* __restrict__ cnt,
                                             float* __restrict__ dis,
                                             int* __restrict__ ecol) {
    __shared__ int lcnt[256];
    __shared__ int lofs[256];
    __shared__ int wsum[4];
    const int b = blockIdx.x, t = threadIdx.x;
    const int start = boff[b], end = boff[b + 1];
    if (t < 256) lcnt[t] = 0;
    __syncthreads();
    for (int e = start + t; e < end; e += 512)
        atomicAdd(&lcnt[epack[e] >> 24], 1);
    __syncthreads();

    const int lane = t & 63, w = t >> 6;
    int c = (t < 256) ? lcnt[t] : 0;
    int v = c;
    #pragma unroll
    for (int off = 1; off < 64; off <<= 1) {
        int u = __shfl_up(v, off);
        if (lane >= off) v += u;
    }
    if (t < 256 && lane == 63) wsum[w] = v;
    __syncthreads();
    if (t < 256) {
        int add = 0;
        #pragma unroll
        for (int i = 0; i < 4; ++i) if (i < w) add += wsum[i];
        int ex = v + add - c;
        lofs[t] = start + ex;
        int n = (b << 8) + t;
        if (n < NUM_NODES) {
            offs[n] = start + ex;
            cnt[n]  = c;
            dis[n]  = rsqrtf((float)max(c, 1));
        }
    }
    __syncthreads();
    for (int e = start + t; e < end; e += 512) {
        unsigned p = epack[e];
        int pos = atomicAdd(&lofs[p >> 24], 1);
        ecol[pos] = (int)(p & 0x00ffffffu);
    }
}

// ---------------- weight prep: Wg0,lw0 -> bf16 fragment table (K=256, 8 tiles) ----------------
__global__ void __launch_bounds__(256) k_wprep(const float* __restrict__ Wg,
                                               const float* __restrict__ Wl,
                                               unsigned short* __restrict__ wfrag) {
    int g = blockIdx.x * 256 + threadIdx.x;     // 4096 total
    if (g >= 4096) return;
    int ks = g >> 9;
    int t  = (g >> 6) & 7;
    int l  = g & 63;
    const float* W = (t < 4) ? Wg : Wl;
    int colg = (t & 3) * 16 + (l & 15);
    int kb = ks * 32 + (l >> 4) * 8;
    unsigned short o[8];
    #pragma unroll
    for (int e = 0; e < 8; ++e) o[e] = f2bf(W[(size_t)(kb + e) * DIM_ID + colg]);
    unsigned short* dst = wfrag + (size_t)g * 8;
    #pragma unroll
    for (int e = 0; e < 8; ++e) dst[e] = o[e];
}

// ---------------- weight prep: 4x 64x64 weights -> bf16 fragment tables (K=64, 4 tiles) ----------------
// order: gw0 | Wg1 | lw1 | gw1, each 512 entries of 8 bf16
__global__ void __launch_bounds__(256) k_wprep64(const float* __restrict__ W0,
                                                 const float* __restrict__ W1,
                                                 const float* __restrict__ W2,
                                                 const float* __restrict__ W3,
                                                 unsigned short* __restrict__ frag) {
    int g = blockIdx.x * 256 + threadIdx.x;     // 2048 total
    if (g >= 2048) return;
    int m = g >> 9;
    int r = g & 511;
    int ks = r >> 8;
    int t  = (r >> 6) & 3;
    int l  = r & 63;
    const float* W = (m == 0) ? W0 : (m == 1) ? W1 : (m == 2) ? W2 : W3;
    int colg = t * 16 + (l & 15);
    int kb = ks * 32 + (l >> 4) * 8;
    unsigned short o[8];
    #pragma unroll
    for (int e = 0; e < 8; ++e) o[e] = f2bf(W[(size_t)(kb + e) * DIM_ID + colg]);
    unsigned short* dst = frag + (size_t)g * 8;
    #pragma unroll
    for (int e = 0; e < 8; ++e) dst[e] = o[e];
}

// ---------------- layer 1 (MFMA): bf16 fragment-direct, fully-unrolled pipelined loads ----------------
__global__ void __launch_bounds__(256, 3) k_l1(
    const unsigned short* __restrict__ xn,
    const unsigned short* __restrict__ wfrag,
    const float* __restrict__ lb,   const float* __restrict__ idemb,
    unsigned short* __restrict__ hbf, unsigned short* __restrict__ xhat)
{
    __shared__ unsigned short st[4][16][68];    // wave-private staging, stride 68
    const int lane = threadIdx.x & 63;
    const int w = threadIdx.x >> 6;
    const int ql = lane & 15, q = lane >> 4;
    const int rowBase = (blockIdx.x * 4 + w) * 16;
    const int row = rowBase + ql;
    const unsigned short* src = xn + (size_t)((row < NUM_NODES) ? row : 0) * DIM_LATENT;

    bf8_t af[8];
    #pragma unroll
    for (int ks = 0; ks < 8; ++ks)
        af[ks] = *reinterpret_cast<const bf8_t*>(src + ks * 32 + q * 8);

    f4_t acc[8];
    #pragma unroll
    for (int t = 0; t < 8; ++t) acc[t] = (f4_t){0.f, 0.f, 0.f, 0.f};

    const bf8_t* wf = reinterpret_cast<const bf8_t*>(wfrag);
    #pragma unroll
    for (int ks = 0; ks < 8; ++ks) {
        #pragma unroll
        for (int t = 0; t < 8; ++t) {
            bf8_t b = wf[(ks * 8 + t) * 64 + lane];
            acc[t] = __builtin_amdgcn_mfma_f32_16x16x32_bf16(af[ks], b, acc[t], 0, 0, 0);
        }
    }

    // ---- phase A: hbf (unscaled; k_hscale applies dis) via LDS -> coalesced uint2 ----
    #pragma unroll
    for (int t = 0; t < 4; ++t)
        #pragma unroll
        for (int reg = 0; reg < 4; ++reg)
            st[w][q * 4 + reg][t * 16 + ql] = f2bf(acc[t][reg]);
    #pragma unroll
    for (int it = 0; it < 4; ++it) {
        int i = it * 64 + lane;
        int r = i >> 4, c8 = i & 15;
        int n = rowBase + r;
        uint2 v = *reinterpret_cast<const uint2*>(&st[w][r][c8 * 4]);
        if (n < NUM_NODES)
            *reinterpret_cast<uint2*>(&hbf[(size_t)n * DIM_ID + c8 * 4]) = v;
    }

    // ---- phase B: xhat = lrelu(a+lb) (+idemb in coalesced phase) ----
    #pragma unroll
    for (int t = 4; t < 8; ++t) {
        int colg = (t - 4) * 16 + ql;
        float lbl = lb[colg];
        #pragma unroll
        for (int reg = 0; reg < 4; ++reg)
            st[w][q * 4 + reg][colg] = f2bf(lrelu(acc[t][reg] + lbl));
    }
    #pragma unroll
    for (int it = 0; it < 4; ++it) {
        int i = it * 64 + lane;
        int r = i >> 4, c8 = i & 15;
        int n = rowBase + r;
        if (n < NUM_NODES) {
            uint2 s = *reinterpret_cast<const uint2*>(&st[w][r][c8 * 4]);
            float4 idv = *reinterpret_cast<const float4*>(&idemb[(size_t)n * DIM_ID + c8 * 4]);
            uint2 o;
            o.x = (unsigned)f2bf(bflo(s.x) + idv.x) | ((unsigned)f2bf(bfhi(s.x) + idv.y) << 16);
            o.y = (unsigned)f2bf(bflo(s.y) + idv.z) | ((unsigned)f2bf(bfhi(s.y) + idv.w) << 16);
            *reinterpret_cast<uint2*>(&xhat[(size_t)n * DIM_ID + c8 * 4]) = o;
        }
    }
}

// ---------------- hbf *= dis (post-scale; uint2 per thread) ----------------
__global__ void __launch_bounds__(256, 8) k_hscale(uint2* __restrict__ hp,
                                                   const float* __restrict__ dis) {
    int t = blockIdx.x * 256 + threadIdx.x;     // 1.6M uint2
    float dn = dis[t >> 4];
    uint2 u = hp[t];
    uint2 o;
    o.x = (unsigned)f2bf(bflo(u.x) * dn) | ((unsigned)f2bf(bfhi(u.x) * dn) << 16);
    o.y = (unsigned)f2bf(bflo(u.y) * dn) | ((unsigned)f2bf(bfhi(u.y) * dn) << 16);
    hp[t] = o;
}

// ---------------- gather: Hb[n] = bf16(dis[n] * sum_e hbf[ecol[e]]) ----------------
// dim-per-lane: one wave per node, lane = dim; edge index via readlane (SALU addr);
// each edge = one coalesced 128B row read; no reduction tail.
__global__ void __launch_bounds__(256, 8) k_gather(
    const unsigned short* __restrict__ hbf, const float* __restrict__ dis,
    const int* __restrict__ offs, const int* __restrict__ cnt,
    const int* __restrict__ ecol, unsigned short* __restrict__ Hb)
{
    const int w = threadIdx.x >> 6;
    const int lane = threadIdx.x & 63;
    const int n = blockIdx.x * 4 + w;

    const float dn = dis[n];
    const int start = offs[n];
    const int m = cnt[n];

    float a0 = 0.f, a1 = 0.f, a2 = 0.f, a3 = 0.f;

    for (int base = 0; base < m; base += 64) {
        int lim = m - base; if (lim > 64) lim = 64;
        int ec = (base + lane < m) ? ecol[start + base + lane] : 0;
        int e = 0;
        for (; e + 4 <= lim; e += 4) {
            int c0 = __shfl(ec, e);
            int c1 = __shfl(ec, e + 1);
            int c2 = __shfl(ec, e + 2);
            int c3 = __shfl(ec, e + 3);
            unsigned short v0 = hbf[(c0 << 6) + lane];
            unsigned short v1 = hbf[(c1 << 6) + lane];
            unsigned short v2 = hbf[(c2 << 6) + lane];
            unsigned short v3 = hbf[(c3 << 6) + lane];
            a0 += bf2f(v0);
            a1 += bf2f(v1);
            a2 += bf2f(v2);
            a3 += bf2f(v3);
        }
        for (; e < lim; ++e) {
            int c0 = __shfl(ec, e);
            a0 += bf2f(hbf[(c0 << 6) + lane]);
        }
    }
    float acc = (a0 + a1) + (a2 + a3);
    Hb[(size_t)n * DIM_ID + lane] = f2bf(acc * dn);
}

// ---------------- mid (MFMA): x1 = lrelu(lrelu(H)@gw0+gb0+xhat1);
//                  hbf = bf16(dis*(x1@Wg1)); xhat2 = bf16(lrelu(x1@lw1+b1)+id) ----------------
__global__ void __launch_bounds__(256, 3) k_mid(
    const unsigned short* __restrict__ Hb, const unsigned short* __restrict__ xhat1,
    const unsigned short* __restrict__ wf64,   // gw0|Wg1|lw1|gw1 frag tables
    const float* __restrict__ gb,  const float* __restrict__ lb1,
    const float* __restrict__ idemb, const float* __restrict__ dis,
    unsigned short* __restrict__ hbf, unsigned short* __restrict__ xhat2)
{
    __shared__ unsigned short x1s[4][16][DIM_ID];   // 8 KB
    __shared__ unsigned short st[4][16][68];        // 8.7 KB epilogue staging
    const int lane = threadIdx.x & 63;
    const int w = threadIdx.x >> 6;
    const int ql = lane & 15, q = lane >> 4;
    const int rowBase = (blockIdx.x * 4 + w) * 16;
    const int rowc = min(rowBase + ql, NUM_NODES - 1);

    // A-frag: lrelu(Hb[row]) in bf16
    bf8_t ha[2];
    #pragma unroll
    for (int ks = 0; ks < 2; ++ks) {
        uint4 u = *reinterpret_cast<const uint4*>(&Hb[(size_t)rowc * DIM_ID + ks * 32 + q * 8]);
        bf8_t a;
        a[0] = (short)f2bf(lrelu(bflo(u.x))); a[1] = (short)f2bf(lrelu(bfhi(u.x)));
        a[2] = (short)f2bf(lrelu(bflo(u.y))); a[3] = (short)f2bf(lrelu(bfhi(u.y)));
        a[4] = (short)f2bf(lrelu(bflo(u.z))); a[5] = (short)f2bf(lrelu(bfhi(u.z)));
        a[6] = (short)f2bf(lrelu(bflo(u.w))); a[7] = (short)f2bf(lrelu(bfhi(u.w)));
        ha[ks] = a;
    }

    const bf8_t* gw0f = reinterpret_cast<const bf8_t*>(wf64);
    f4_t acc1[4];
    #pragma unroll
    for (int t = 0; t < 4; ++t) acc1[t] = (f4_t){0.f, 0.f, 0.f, 0.f};
    #pragma unroll
    for (int ks = 0; ks < 2; ++ks)
        #pragma unroll
        for (int t = 0; t < 4; ++t)
            acc1[t] = __builtin_amdgcn_mfma_f32_16x16x32_bf16(ha[ks], gw0f[(ks * 4 + t) * 64 + lane], acc1[t], 0, 0, 0);

    int nn[4];
    #pragma unroll
    for (int reg = 0; reg < 4; ++reg) nn[reg] = rowBase + q * 4 + reg;

    // x1 = lrelu(acc1 + gb + xhat1) -> bf16 LDS
    #pragma unroll
    for (int t = 0; t < 4; ++t) {
        int colg = t * 16 + ql;
        float gbl = gb[colg];
        #pragma unroll
        for (int reg = 0; reg < 4; ++reg) {
            float xh = bf2f(xhat1[(size_t)min(nn[reg], NUM_NODES - 1) * DIM_ID + colg]);
            x1s[w][q * 4 + reg][colg] = f2bf(lrelu(acc1[t][reg] + gbl + xh));
        }
    }
    __syncthreads();

    // A2-frag from LDS
    bf8_t xa[2];
    #pragma unroll
    for (int ks = 0; ks < 2; ++ks)
        xa[ks] = *reinterpret_cast<const bf8_t*>(&x1s[w][ql][ks * 32 + q * 8]);

    const bf8_t* wg1f = reinterpret_cast<const bf8_t*>(wf64 + 512 * 8);
    const bf8_t* lw1f = reinterpret_cast<const bf8_t*>(wf64 + 1024 * 8);
    f4_t acc2[8];
    #pragma unroll
    for (int t = 0; t < 8; ++t) acc2[t] = (f4_t){0.f, 0.f, 0.f, 0.f};
    #pragma unroll
    for (int ks = 0; ks < 2; ++ks) {
        #pragma unroll
        for (int t = 0; t < 4; ++t)
            acc2[t] = __builtin_amdgcn_mfma_f32_16x16x32_bf16(xa[ks], wg1f[(ks * 4 + t) * 64 + lane], acc2[t], 0, 0, 0);
        #pragma unroll
        for (int t = 0; t < 4; ++t)
            acc2[4 + t] = __builtin_amdgcn_mfma_f32_16x16x32_bf16(xa[ks], lw1f[(ks * 4 + t) * 64 + lane], acc2[4 + t], 0, 0, 0);
    }

    float dn[4];
    #pragma unroll
    for (int reg = 0; reg < 4; ++reg)
        dn[reg] = (nn[reg] < NUM_NODES) ? dis[nn[reg]] : 0.0f;

    // ---- phase A: hbf = acc2[0..3]*dn via LDS -> coalesced uint2 ----
    #pragma unroll
    for (int t = 0; t < 4; ++t)
        #pragma unroll
        for (int reg = 0; reg < 4; ++reg)
            st[w][q * 4 + reg][t * 16 + ql] = f2bf(acc2[t][reg] * dn[reg]);
    #pragma unroll
    for (int it = 0; it < 4; ++it) {
        int i = it * 64 + lane;
        int r = i >> 4, c8 = i & 15;
        int n = rowBase + r;
        uint2 v = *reinterpret_cast<const uint2*>(&st[w][r][c8 * 4]);
        if (n < NUM_NODES)
            *reinterpret_cast<uint2*>(&hbf[(size_t)n * DIM_ID + c8 * 4]) = v;
    }

    // ---- phase B: xhat2 = lrelu(acc2[4..7]+lb1) (+idemb coalesced) ----
    #pragma unroll
    for (int t = 0; t < 4; ++t) {
        int colg = t * 16 + ql;
        float lbl = lb1[colg];
        #pragma unroll
        for (int reg = 0; reg < 4; ++reg)
            st[w][q * 4 + reg][colg] = f2bf(lrelu(acc2[4 + t][reg] + lbl));
    }
    #pragma unroll
    for (int it = 0; it < 4; ++it) {
        int i = it * 64 + lane;
        int r = i >> 4, c8 = i & 15;
        int n = rowBase + r;
        if (n < NUM_NODES) {
            uint2 s = *reinterpret_cast<const uint2*>(&st[w][r][c8 * 4]);
            float4 idv = *reinterpret_cast<const float4*>(&idemb[(size_t)n * DIM_ID + c8 * 4]);
            uint2 o;
            o.x = (unsigned)f2bf(bflo(s.x) + idv.x) | ((unsigned)f2bf(bfhi(s.x) + idv.y) << 16);
            o.y = (unsigned)f2bf(bflo(s.y) + idv.z) | ((unsigned)f2bf(bfhi(s.y) + idv.w) << 16);
            *reinterpret_cast<uint2*>(&xhat2[(size_t)n * DIM_ID + c8 * 4]) = o;
        }
    }
}

// ---------------- final (MFMA): out = lrelu(lrelu(H2)@gw1 + gb1 + xhat2) ----------------
__global__ void __launch_bounds__(256, 3) k_final(
    const unsigned short* __restrict__ Hb, const unsigned short* __restrict__ xhat,
    const unsigned short* __restrict__ wf64,
    const float* __restrict__ gb, float* __restrict__ out)
{
    const int lane = threadIdx.x & 63;
    const int w = threadIdx.x >> 6;
    const int ql = lane & 15, q = lane >> 4;
    const int rowBase = (blockIdx.x * 4 + w) * 16;
    const int rowc = min(rowBase + ql, NUM_NODES - 1);

    bf8_t ha[2];
    #pragma unroll
    for (int ks = 0; ks < 2; ++ks) {
        uint4 u = *reinterpret_cast<const uint4*>(&Hb[(size_t)rowc * DIM_ID + ks * 32 + q * 8]);
        bf8_t a;
        a[0] = (short)f2bf(lrelu(bflo(u.x))); a[1] = (short)f2bf(lrelu(bfhi(u.x)));
        a[2] = (short)f2bf(lrelu(bflo(u.y))); a[3] = (short)f2bf(lrelu(bfhi(u.y)));
        a[4] = (short)f2bf(lrelu(bflo(u.z))); a[5] = (short)f2bf(lrelu(bfhi(u.z)));
        a[6] = (short)f2bf(lrelu(bflo(u.w))); a[7] = (short)f2bf(lrelu(bfhi(u.w)));
        ha[ks] = a;
    }

    const bf8_t* gw1f = reinterpret_cast<const bf8_t*>(wf64 + 1536 * 8);
    f4_t acc[4];
    #pragma unroll
    for (int t = 0; t < 4; ++t) acc[t] = (f4_t){0.f, 0.f, 0.f, 0.f};
    #pragma unroll
    for (int ks = 0; ks < 2; ++ks)
        #pragma unroll
        for (int t = 0; t < 4; ++t)
            acc[t] = __builtin_amdgcn_mfma_f32_16x16x32_bf16(ha[ks], gw1f[(ks * 4 + t) * 64 + lane], acc[t], 0, 0, 0);

    int nn[4];
    #pragma unroll
    for (int reg = 0; reg < 4; ++reg) nn[reg] = rowBase + q * 4 + reg;

    #pragma unroll
    for (int t = 0; t < 4; ++t) {
        int colg = t * 16 + ql;
        float gbl = gb[colg];
        #pragma unroll
        for (int reg = 0; reg < 4; ++reg)
            if (nn[reg] < NUM_NODES) {
                size_t o = (size_t)nn[reg] * DIM_ID + colg;
                out[o] = lrelu(acc[t][reg] + gbl + bf2f(xhat[o]));
            }
    }
}

extern "C" void kernel_launch(void* const* d_in, const int* in_sizes, int n_in,
                              void* d_out, int out_size, void* d_ws, size_t ws_size,
                              hipStream_t stream)
{
    const float* features = (const float*)d_in[0];
    const float* idemb    = (const float*)d_in[1];
    const float* pref     = (const float*)d_in[2];
    const float* Wg0      = (const float*)d_in[3];
    const float* Wg1      = (const float*)d_in[4];
    const float* lw0      = (const float*)d_in[5];
    const float* lb0      = (const float*)d_in[6];
    const float* lw1      = (const float*)d_in[7];
    const float* lb1      = (const float*)d_in[8];
    const float* gw0      = (const float*)d_in[9];
    const float* gb0      = (const float*)d_in[10];
    const float* gw1      = (const float*)d_in[11];
    const float* gb1      = (const float*)d_in[12];
    const int*   edges    = (const int*)d_in[13];
    const int*   row      = edges;
    const int*   col      = edges + NUM_EDGES;

    char* ws = (char*)d_ws;
    int*      hist  = (int*)(ws + 0);             // 384,160 B (pad 512K)
    int*      bcnt  = (int*)(ws + 524288);        // 4 KB
    int*      boff  = (int*)(ws + 528384);        // 4 KB
    int*      offs  = (int*)(ws + 532480);        // 512K
    int*      cnt   = (int*)(ws + 1056768);       // 512K
    float*    dis   = (float*)(ws + 1581056);     // 512K
    unsigned short* wfrag = (unsigned short*)(ws + 2105344);   // 64 KB (layer-1 table)
    unsigned short* wf64  = (unsigned short*)(ws + 2170880);   // 32 KB (gw0|Wg1|lw1|gw1)
    unsigned short* xn    = (unsigned short*)(ws + 2236416);   // 51.2 MB (dead after k_l1)
    //   aliases within xn region (all born after k_l1 completes):
    int*      ecol  = (int*)(ws + 2236416);                    // 8 MB
    unsigned* epack = (unsigned*)(ws + 10625024);              // 8 MB
    unsigned short* Hbf   = (unsigned short*)(ws + 19013632);  // 12.8 MB (ends 31.8 MB < 53.4)
    unsigned short* hbf   = (unsigned short*)(ws + 53436416);  // 12.8 MB
    unsigned short* xhatb = (unsigned short*)(ws + 66236416);  // 12.8 MB -> 79.0 MB total
    float* out   = (float*)d_out;

    const int l1Blocks = (NUM_NODES + 63) / 64;     // 1563
    const int gatherBlocks = NUM_NODES / 4;         // 25000

    // ---- weight prep + normalize + bucket histogram/scan ----
    k_wprep<<<16, 256, 0, stream>>>(Wg0, lw0, wfrag);
    k_wprep64<<<8, 256, 0, stream>>>(gw0, Wg1, lw1, gw1, wf64);
    k_xnorm<<<NUM_NODES / 4, 256, 0, stream>>>(pref, features, xn);
    k_hist<<<NCHUNK, 256, 0, stream>>>(row, hist);
    k_off1<<<NBUCKET, 256, 0, stream>>>(hist, bcnt);
    k_bscan<<<1, 512, 0, stream>>>(bcnt, boff);

    // ---- layer 1 GEMM (before CSR so xn region can be recycled) ----
    k_l1<<<l1Blocks, 256, 0, stream>>>(xn, wfrag, lb0, idemb, hbf, xhatb);

    // ---- CSR build into recycled xn region ----
    k_bin2<<<NCHUNK, 256, 0, stream>>>(row, col, hist, boff, epack);
    k_csr<<<NBUCKET, 512, 0, stream>>>(epack, boff, offs, cnt, dis, ecol);
    k_hscale<<<NUM_NODES * 16 / 256, 256, 0, stream>>>((uint2*)hbf, dis);

    // ---- layer 1 aggregate ----
    k_gather<<<gatherBlocks, 256, 0, stream>>>(hbf, dis, offs, cnt, ecol, Hbf);

    // ---- combine1 + layer2 pre (fused, MFMA) ----
    k_mid<<<l1Blocks, 256, 0, stream>>>(Hbf, xhatb, wf64, gb0, lb1, idemb, dis,
                                        hbf, xhatb);

    // ---- layer 2 aggregate + final combine (MFMA) ----
    k_gather<<<gatherBlocks, 256, 0, stream>>>(hbf, dis, offs, cnt, ecol, Hbf);
    k_final<<<l1Blocks, 256, 0, stream>>>(Hbf, xhatb, wf64, gb1, out);
}

// Round 14
// 234.994 us; speedup vs baseline: 1.1370x; 1.1370x over previous
//
#include <hip/hip_runtime.h>

#define NUM_USER   50000
#define NUM_ITEM   50000
#define NUM_NODES  100000
#define DIM_LATENT 256
#define DIM_ID     64
#define NUM_EDGES  2000000
#define NBUCKET    391        // ceil(100000/256) buckets of 256 nodes
#define BPB        8192       // edges per chunk for counting sort
#define NCHUNK     245        // ceil(NUM_EDGES/BPB)
#define HSTRIDE    392

typedef __attribute__((ext_vector_type(8))) short bf8_t;
typedef __attribute__((ext_vector_type(4))) float f4_t;
typedef __attribute__((ext_vector_type(2))) float f2_t;

static __device__ __forceinline__ float lrelu(float x) {
    return x > 0.0f ? x : 0.01f * x;
}
static __device__ __forceinline__ unsigned short f2bf(float f) {
    unsigned u = __float_as_uint(f);
    u += 0x7fff + ((u >> 16) & 1);
    return (unsigned short)(u >> 16);
}
static __device__ __forceinline__ float bf2f(unsigned short u) {
    return __uint_as_float(((unsigned)u) << 16);
}
static __device__ __forceinline__ float bflo(unsigned u) {
    return __uint_as_float(u << 16);
}
static __device__ __forceinline__ float bfhi(unsigned u) {
    return __uint_as_float(u & 0xffff0000u);
}

// ---------------- normalize rows -> bf16 xn ----------------
__global__ void __launch_bounds__(256, 8) k_xnorm(const float* __restrict__ pref,
                                                  const float* __restrict__ feat,
                                                  unsigned short* __restrict__ xn) {
    const int w = threadIdx.x >> 6;
    const int lane = threadIdx.x & 63;
    const int n = blockIdx.x * 4 + w;
    const float* src = (n < NUM_USER) ? (pref + (size_t)n * DIM_LATENT)
                                      : (feat + (size_t)(n - NUM_USER) * DIM_LATENT);
    float4 v = reinterpret_cast<const float4*>(src)[lane];
    float ss = v.x*v.x + v.y*v.y + v.z*v.z + v.w*v.w;
    #pragma unroll
    for (int off = 32; off >= 1; off >>= 1) ss += __shfl_xor(ss, off);
    float sc = 1.0f / fmaxf(sqrtf(ss), 1e-12f);
    ushort4 p;
    p.x = f2bf(v.x * sc); p.y = f2bf(v.y * sc);
    p.z = f2bf(v.z * sc); p.w = f2bf(v.w * sc);
    *reinterpret_cast<ushort4*>(&xn[(size_t)n * DIM_LATENT + lane * 4]) = p;
}

// ---------------- pass 1: per-chunk bucket histogram (LDS atomics only) ----------------
__global__ void __launch_bounds__(256) k_hist(const int* __restrict__ row,
                                              int* __restrict__ hist) {
    __shared__ int lh[NBUCKET];
    const int g = blockIdx.x, t = threadIdx.x;
    for (int i = t; i < NBUCKET; i += 256) lh[i] = 0;
    __syncthreads();
    const int base = g * BPB;
    for (int i = 0; i < BPB; i += 256) {
        int e = base + i + t;
        if (e < NUM_EDGES) atomicAdd(&lh[row[e] >> 8], 1);
    }
    __syncthreads();
    for (int i = t; i < NBUCKET; i += 256) hist[g * HSTRIDE + i] = lh[i];
}

// ---------------- pass 2a: per-bucket scan over chunks; hist -> exclusive, bcnt ----------------
__global__ void __launch_bounds__(256) k_off1(int* __restrict__ hist,
                                              int* __restrict__ bcnt) {
    __shared__ int wsum[4];
    const int b = blockIdx.x, t = threadIdx.x;
    const int lane = t & 63, w = t >> 6;
    int c = (t < NCHUNK) ? hist[t * HSTRIDE + b] : 0;
    int v = c;
    #pragma unroll
    for (int off = 1; off < 64; off <<= 1) {
        int u = __shfl_up(v, off);
        if (lane >= off) v += u;
    }
    if (lane == 63) wsum[w] = v;
    __syncthreads();
    int add = 0;
    #pragma unroll
    for (int i = 0; i < 4; ++i) if (i < w) add += wsum[i];
    int incl = v + add;
    if (t < NCHUNK) hist[t * HSTRIDE + b] = incl - c;
    if (t == 255) bcnt[b] = incl;
}

// ---------------- pass 2b: exclusive scan over 391 bucket counts -> boff ----------------
__global__ void __launch_bounds__(512) k_bscan(const int* __restrict__ bcnt,
                                               int* __restrict__ boff) {
    __shared__ int wsum[8];
    const int t = threadIdx.x;
    const int lane = t & 63, w = t >> 6;
    int c = (t < NBUCKET) ? bcnt[t] : 0;
    int v = c;
    #pragma unroll
    for (int off = 1; off < 64; off <<= 1) {
        int u = __shfl_up(v, off);
        if (lane >= off) v += u;
    }
    if (lane == 63) wsum[w] = v;
    __syncthreads();
    int add = 0;
    #pragma unroll
    for (int i = 0; i < 8; ++i) if (i < w) add += wsum[i];
    int ex = v + add - c;
    if (t < NBUCKET) boff[t] = ex;
    if (t == NBUCKET - 1) boff[NBUCKET] = ex + c;   // == NUM_EDGES
}

// ---------------- pass 3: scatter packed edges to bucket-contiguous epack ----------------
// pack: (local_node << 24) | col   (col < 2^17)
__global__ void __launch_bounds__(256) k_bin2(const int* __restrict__ row,
                                              const int* __restrict__ col,
                                              const int* __restrict__ hist,
                                              const int* __restrict__ boff,
                                              unsigned* __restrict__ epack) {
    __shared__ int curs[NBUCKET];
    const int g = blockIdx.x, t = threadIdx.x;
    for (int i = t; i < NBUCKET; i += 256) curs[i] = boff[i] + hist[g * HSTRIDE + i];
    __syncthreads();
    const int base = g * BPB;
    for (int i = 0; i < BPB; i += 256) {
        int e = base + i + t;
        if (e < NUM_EDGES) {
            int r = row[e];
            int pos = atomicAdd(&curs[r >> 8], 1);
            epack[pos] = ((unsigned)(r & 255) << 24) | (unsigned)col[e];
        }
    }
}

// ---------------- pass 4: bucket-local exact CSR: offs, cnt, dis, ecol ----------------
__global__ void __launch_bounds__(512) k_csr(const unsigned* __restrict__ epack,
                                             const int* __restrict__ boff,
                                             int* __restrict__ offs,
                                             int* __restrict__ cnt,
                                             float* __restrict__ dis,
                                             int* __restrict__ ecol) {
    __shared__ int lcnt[256];
    __shared__ int lofs[256];
    __shared__ int wsum[4];
    const int b = blockIdx.x, t = threadIdx.x;
    const int start = boff[b], end = boff[b + 1];
    if (t < 256) lcnt[t] = 0;
    __syncthreads();
    for (int e = start + t; e < end; e += 512)
        atomicAdd(&lcnt[epack[e] >> 24], 1);
    __syncthreads();

    const int lane = t & 63, w = t >> 6;
    int c = (t < 256) ? lcnt[t] : 0;
    int v = c;
    #pragma unroll
    for (int off = 1; off < 64; off <<= 1) {
        int u = __shfl_up(v, off);
        if (lane >= off) v += u;
    }
    if (t < 256 && lane == 63) wsum[w] = v;
    __syncthreads();
    if (t < 256) {
        int add = 0;
        #pragma unroll
        for (int i = 0; i < 4; ++i) if (i < w) add += wsum[i];
        int ex = v + add - c;
        lofs[t] = start + ex;
        int n = (b << 8) + t;
        if (n < NUM_NODES) {
            offs[n] = start + ex;
            cnt[n]  = c;
            dis[n]  = rsqrtf((float)max(c, 1));
        }
    }
    __syncthreads();
    for (int e = start + t; e < end; e += 512) {
        unsigned p = epack[e];
        int pos = atomicAdd(&lofs[p >> 24], 1);
        ecol[pos] = (int)(p & 0x00ffffffu);
    }
}

// ---------------- weight prep: Wg0,lw0 -> bf16 fragment table (K=256, 8 tiles) ----------------
__global__ void __launch_bounds__(256) k_wprep(const float* __restrict__ Wg,
                                               const float* __restrict__ Wl,
                                               unsigned short* __restrict__ wfrag) {
    int g = blockIdx.x * 256 + threadIdx.x;     // 4096 total
    if (g >= 4096) return;
    int ks = g >> 9;
    int t  = (g >> 6) & 7;
    int l  = g & 63;
    const float* W = (t < 4) ? Wg : Wl;
    int colg = (t & 3) * 16 + (l & 15);
    int kb = ks * 32 + (l >> 4) * 8;
    unsigned short o[8];
    #pragma unroll
    for (int e = 0; e < 8; ++e) o[e] = f2bf(W[(size_t)(kb + e) * DIM_ID + colg]);
    unsigned short* dst = wfrag + (size_t)g * 8;
    #pragma unroll
    for (int e = 0; e < 8; ++e) dst[e] = o[e];
}

// ---------------- weight prep: 4x 64x64 weights -> bf16 fragment tables (K=64, 4 tiles) ----------------
// order: gw0 | Wg1 | lw1 | gw1, each 512 entries of 8 bf16
__global__ void __launch_bounds__(256) k_wprep64(const float* __restrict__ W0,
                                                 const float* __restrict__ W1,
                                                 const float* __restrict__ W2,
                                                 const float* __restrict__ W3,
                                                 unsigned short* __restrict__ frag) {
    int g = blockIdx.x * 256 + threadIdx.x;     // 2048 total
    if (g >= 2048) return;
    int m = g >> 9;
    int r = g & 511;
    int ks = r >> 8;
    int t  = (r >> 6) & 3;
    int l  = r & 63;
    const float* W = (m == 0) ? W0 : (m == 1) ? W1 : (m == 2) ? W2 : W3;
    int colg = t * 16 + (l & 15);
    int kb = ks * 32 + (l >> 4) * 8;
    unsigned short o[8];
    #pragma unroll
    for (int e = 0; e < 8; ++e) o[e] = f2bf(W[(size_t)(kb + e) * DIM_ID + colg]);
    unsigned short* dst = frag + (size_t)g * 8;
    #pragma unroll
    for (int e = 0; e < 8; ++e) dst[e] = o[e];
}

// ---------------- layer 1 (MFMA): bf16 fragment-direct, fully-unrolled pipelined loads ----------------
__global__ void __launch_bounds__(256, 3) k_l1(
    const unsigned short* __restrict__ xn,
    const unsigned short* __restrict__ wfrag,
    const float* __restrict__ lb,   const float* __restrict__ idemb,
    unsigned short* __restrict__ hbf, unsigned short* __restrict__ xhat)
{
    __shared__ unsigned short st[4][16][68];    // wave-private staging, stride 68
    const int lane = threadIdx.x & 63;
    const int w = threadIdx.x >> 6;
    const int ql = lane & 15, q = lane >> 4;
    const int rowBase = (blockIdx.x * 4 + w) * 16;
    const int row = rowBase + ql;
    const unsigned short* src = xn + (size_t)((row < NUM_NODES) ? row : 0) * DIM_LATENT;

    bf8_t af[8];
    #pragma unroll
    for (int ks = 0; ks < 8; ++ks)
        af[ks] = *reinterpret_cast<const bf8_t*>(src + ks * 32 + q * 8);

    f4_t acc[8];
    #pragma unroll
    for (int t = 0; t < 8; ++t) acc[t] = (f4_t){0.f, 0.f, 0.f, 0.f};

    const bf8_t* wf = reinterpret_cast<const bf8_t*>(wfrag);
    #pragma unroll
    for (int ks = 0; ks < 8; ++ks) {
        #pragma unroll
        for (int t = 0; t < 8; ++t) {
            bf8_t b = wf[(ks * 8 + t) * 64 + lane];
            acc[t] = __builtin_amdgcn_mfma_f32_16x16x32_bf16(af[ks], b, acc[t], 0, 0, 0);
        }
    }

    // ---- phase A: hbf (unscaled; k_hcvt applies dis + fp8) via LDS -> coalesced uint2 ----
    #pragma unroll
    for (int t = 0; t < 4; ++t)
        #pragma unroll
        for (int reg = 0; reg < 4; ++reg)
            st[w][q * 4 + reg][t * 16 + ql] = f2bf(acc[t][reg]);
    #pragma unroll
    for (int it = 0; it < 4; ++it) {
        int i = it * 64 + lane;
        int r = i >> 4, c8 = i & 15;
        int n = rowBase + r;
        uint2 v = *reinterpret_cast<const uint2*>(&st[w][r][c8 * 4]);
        if (n < NUM_NODES)
            *reinterpret_cast<uint2*>(&hbf[(size_t)n * DIM_ID + c8 * 4]) = v;
    }

    // ---- phase B: xhat = lrelu(a+lb) (+idemb in coalesced phase) ----
    #pragma unroll
    for (int t = 4; t < 8; ++t) {
        int colg = (t - 4) * 16 + ql;
        float lbl = lb[colg];
        #pragma unroll
        for (int reg = 0; reg < 4; ++reg)
            st[w][q * 4 + reg][colg] = f2bf(lrelu(acc[t][reg] + lbl));
    }
    #pragma unroll
    for (int it = 0; it < 4; ++it) {
        int i = it * 64 + lane;
        int r = i >> 4, c8 = i & 15;
        int n = rowBase + r;
        if (n < NUM_NODES) {
            uint2 s = *reinterpret_cast<const uint2*>(&st[w][r][c8 * 4]);
            float4 idv = *reinterpret_cast<const float4*>(&idemb[(size_t)n * DIM_ID + c8 * 4]);
            uint2 o;
            o.x = (unsigned)f2bf(bflo(s.x) + idv.x) | ((unsigned)f2bf(bfhi(s.x) + idv.y) << 16);
            o.y = (unsigned)f2bf(bflo(s.y) + idv.z) | ((unsigned)f2bf(bfhi(s.y) + idv.w) << 16);
            *reinterpret_cast<uint2*>(&xhat[(size_t)n * DIM_ID + c8 * 4]) = o;
        }
    }
}

// ---------------- bf16 hbf (unscaled) + dis -> fp8 table ----------------
__global__ void __launch_bounds__(256, 8) k_hcvt(const uint2* __restrict__ hp,
                                                 const float* __restrict__ dis,
                                                 unsigned* __restrict__ out) {
    int t = blockIdx.x * 256 + threadIdx.x;     // 1.6M threads, 4 dims each
    float dn = dis[t >> 4];
    uint2 u = hp[t];
    float v0 = bflo(u.x) * dn, v1 = bfhi(u.x) * dn;
    float v2 = bflo(u.y) * dn, v3 = bfhi(u.y) * dn;
    int p = __builtin_amdgcn_cvt_pk_fp8_f32(v0, v1, 0, false);
    p = __builtin_amdgcn_cvt_pk_fp8_f32(v2, v3, p, true);
    out[t] = (unsigned)p;
}

// ---------------- bf16 hbf (already scaled) -> fp8 table ----------------
__global__ void __launch_bounds__(256, 8) k_hcvt1(const uint2* __restrict__ hp,
                                                  unsigned* __restrict__ out) {
    int t = blockIdx.x * 256 + threadIdx.x;
    uint2 u = hp[t];
    int p = __builtin_amdgcn_cvt_pk_fp8_f32(bflo(u.x), bfhi(u.x), 0, false);
    p = __builtin_amdgcn_cvt_pk_fp8_f32(bflo(u.y), bfhi(u.y), p, true);
    out[t] = (unsigned)p;
}

// ---------------- gather: Hb[n] = bf16(dis[n] * sum_e hbf8[ecol[e]])  (fp8 table) ----------------
// eighth-wave per edge (uint2 = 8 fp8 per lane); 64B row = 1 line per edge
__global__ void __launch_bounds__(256, 8) k_gather(
    const unsigned char* __restrict__ hbf8, const float* __restrict__ dis,
    const int* __restrict__ offs, const int* __restrict__ cnt,
    const int* __restrict__ ecol, unsigned short* __restrict__ Hb)
{
    const int w = threadIdx.x >> 6;
    const int lane = threadIdx.x & 63;
    const int g = lane >> 3;      // edge slot 0..7
    const int k = lane & 7;       // dim octet 0..7
    const int n = blockIdx.x * 4 + w;

    const float dn = dis[n];
    const int start = offs[n];
    const int m = cnt[n];

    f2_t s01 = {0.f, 0.f}, s23 = {0.f, 0.f}, s45 = {0.f, 0.f}, s67 = {0.f, 0.f};

    for (int base = 0; base < m; base += 64) {
        int e = base + lane;
        int ec = (e < m) ? ecol[start + e] : 0;
        int lim = m - base; if (lim > 64) lim = 64;
        int nj = (lim + 7) >> 3;
        for (int jj = 0; jj < nj; jj += 4) {
            int i0 = jj * 8 + g, i1 = i0 + 8, i2 = i0 + 16, i3 = i0 + 24;
            int c0 = __shfl(ec, i0), c1 = __shfl(ec, i1);
            int c2 = __shfl(ec, i2), c3 = __shfl(ec, i3);
            uint2 u0 = make_uint2(0u,0u), u1 = make_uint2(0u,0u);
            uint2 u2 = make_uint2(0u,0u), u3 = make_uint2(0u,0u);
            if (i0 < lim) u0 = *reinterpret_cast<const uint2*>(hbf8 + (size_t)(c0 << 6) + (k << 3));
            if (i1 < lim) u1 = *reinterpret_cast<const uint2*>(hbf8 + (size_t)(c1 << 6) + (k << 3));
            if (i2 < lim) u2 = *reinterpret_cast<const uint2*>(hbf8 + (size_t)(c2 << 6) + (k << 3));
            if (i3 < lim) u3 = *reinterpret_cast<const uint2*>(hbf8 + (size_t)(c3 << 6) + (k << 3));
            s01 += __builtin_amdgcn_cvt_pk_f32_fp8(u0.x, false);
            s23 += __builtin_amdgcn_cvt_pk_f32_fp8(u0.x, true);
            s45 += __builtin_amdgcn_cvt_pk_f32_fp8(u0.y, false);
            s67 += __builtin_amdgcn_cvt_pk_f32_fp8(u0.y, true);
            s01 += __builtin_amdgcn_cvt_pk_f32_fp8(u1.x, false);
            s23 += __builtin_amdgcn_cvt_pk_f32_fp8(u1.x, true);
            s45 += __builtin_amdgcn_cvt_pk_f32_fp8(u1.y, false);
            s67 += __builtin_amdgcn_cvt_pk_f32_fp8(u1.y, true);
            s01 += __builtin_amdgcn_cvt_pk_f32_fp8(u2.x, false);
            s23 += __builtin_amdgcn_cvt_pk_f32_fp8(u2.x, true);
            s45 += __builtin_amdgcn_cvt_pk_f32_fp8(u2.y, false);
            s67 += __builtin_amdgcn_cvt_pk_f32_fp8(u2.y, true);
            s01 += __builtin_amdgcn_cvt_pk_f32_fp8(u3.x, false);
            s23 += __builtin_amdgcn_cvt_pk_f32_fp8(u3.x, true);
            s45 += __builtin_amdgcn_cvt_pk_f32_fp8(u3.y, false);
            s67 += __builtin_amdgcn_cvt_pk_f32_fp8(u3.y, true);
        }
    }
    float a0 = s01.x, a1 = s01.y, a2 = s23.x, a3 = s23.y;
    float a4 = s45.x, a5 = s45.y, a6 = s67.x, a7 = s67.y;
    #pragma unroll
    for (int off = 8; off <= 32; off <<= 1) {
        a0 += __shfl_xor(a0, off); a1 += __shfl_xor(a1, off);
        a2 += __shfl_xor(a2, off); a3 += __shfl_xor(a3, off);
        a4 += __shfl_xor(a4, off); a5 += __shfl_xor(a5, off);
        a6 += __shfl_xor(a6, off); a7 += __shfl_xor(a7, off);
    }
    if (lane < 8) {
        uint4 o;
        o.x = (unsigned)f2bf(a0 * dn) | ((unsigned)f2bf(a1 * dn) << 16);
        o.y = (unsigned)f2bf(a2 * dn) | ((unsigned)f2bf(a3 * dn) << 16);
        o.z = (unsigned)f2bf(a4 * dn) | ((unsigned)f2bf(a5 * dn) << 16);
        o.w = (unsigned)f2bf(a6 * dn) | ((unsigned)f2bf(a7 * dn) << 16);
        *reinterpret_cast<uint4*>(&Hb[(size_t)n * DIM_ID + lane * 8]) = o;
    }
}

// ---------------- mid (MFMA): x1 = lrelu(lrelu(H)@gw0+gb0+xhat1);
//                  hbf = bf16(dis*(x1@Wg1)); xhat2 = bf16(lrelu(x1@lw1+b1)+id) ----------------
__global__ void __launch_bounds__(256, 3) k_mid(
    const unsigned short* __restrict__ Hb, const unsigned short* __restrict__ xhat1,
    const unsigned short* __restrict__ wf64,   // gw0|Wg1|lw1|gw1 frag tables
    const float* __restrict__ gb,  const float* __restrict__ lb1,
    const float* __restrict__ idemb, const float* __restrict__ dis,
    unsigned short* __restrict__ hbf, unsigned short* __restrict__ xhat2)
{
    __shared__ unsigned short x1s[4][16][DIM_ID];   // 8 KB
    __shared__ unsigned short st[4][16][68];        // 8.7 KB epilogue staging
    const int lane = threadIdx.x & 63;
    const int w = threadIdx.x >> 6;
    const int ql = lane & 15, q = lane >> 4;
    const int rowBase = (blockIdx.x * 4 + w) * 16;
    const int rowc = min(rowBase + ql, NUM_NODES - 1);

    // A-frag: lrelu(Hb[row]) in bf16
    bf8_t ha[2];
    #pragma unroll
    for (int ks = 0; ks < 2; ++ks) {
        uint4 u = *reinterpret_cast<const uint4*>(&Hb[(size_t)rowc * DIM_ID + ks * 32 + q * 8]);
        bf8_t a;
        a[0] = (short)f2bf(lrelu(bflo(u.x))); a[1] = (short)f2bf(lrelu(bfhi(u.x)));
        a[2] = (short)f2bf(lrelu(bflo(u.y))); a[3] = (short)f2bf(lrelu(bfhi(u.y)));
        a[4] = (short)f2bf(lrelu(bflo(u.z))); a[5] = (short)f2bf(lrelu(bfhi(u.z)));
        a[6] = (short)f2bf(lrelu(bflo(u.w))); a[7] = (short)f2bf(lrelu(bfhi(u.w)));
        ha[ks] = a;
    }

    const bf8_t* gw0f = reinterpret_cast<const bf8_t*>(wf64);
    f4_t acc1[4];
    #pragma unroll
    for (int t = 0; t < 4; ++t) acc1[t] = (f4_t){0.f, 0.f, 0.f, 0.f};
    #pragma unroll
    for (int ks = 0; ks < 2; ++ks)
        #pragma unroll
        for (int t = 0; t < 4; ++t)
            acc1[t] = __builtin_amdgcn_mfma_f32_16x16x32_bf16(ha[ks], gw0f[(ks * 4 + t) * 64 + lane], acc1[t], 0, 0, 0);

    int nn[4];
    #pragma unroll
    for (int reg = 0; reg < 4; ++reg) nn[reg] = rowBase + q * 4 + reg;

    // x1 = lrelu(acc1 + gb + xhat1) -> bf16 LDS
    #pragma unroll
    for (int t = 0; t < 4; ++t) {
        int colg = t * 16 + ql;
        float gbl = gb[colg];
        #pragma unroll
        for (int reg = 0; reg < 4; ++reg) {
            float xh = bf2f(xhat1[(size_t)min(nn[reg], NUM_NODES - 1) * DIM_ID + colg]);
            x1s[w][q * 4 + reg][colg] = f2bf(lrelu(acc1[t][reg] + gbl + xh));
        }
    }
    __syncthreads();

    // A2-frag from LDS
    bf8_t xa[2];
    #pragma unroll
    for (int ks = 0; ks < 2; ++ks)
        xa[ks] = *reinterpret_cast<const bf8_t*>(&x1s[w][ql][ks * 32 + q * 8]);

    const bf8_t* wg1f = reinterpret_cast<const bf8_t*>(wf64 + 512 * 8);
    const bf8_t* lw1f = reinterpret_cast<const bf8_t*>(wf64 + 1024 * 8);
    f4_t acc2[8];
    #pragma unroll
    for (int t = 0; t < 8; ++t) acc2[t] = (f4_t){0.f, 0.f, 0.f, 0.f};
    #pragma unroll
    for (int ks = 0; ks < 2; ++ks) {
        #pragma unroll
        for (int t = 0; t < 4; ++t)
            acc2[t] = __builtin_amdgcn_mfma_f32_16x16x32_bf16(xa[ks], wg1f[(ks * 4 + t) * 64 + lane], acc2[t], 0, 0, 0);
        #pragma unroll
        for (int t = 0; t < 4; ++t)
            acc2[4 + t] = __builtin_amdgcn_mfma_f32_16x16x32_bf16(xa[ks], lw1f[(ks * 4 + t) * 64 + lane], acc2[4 + t], 0, 0, 0);
    }

    float dn[4];
    #pragma unroll
    for (int reg = 0; reg < 4; ++reg)
        dn[reg] = (nn[reg] < NUM_NODES) ? dis[nn[reg]] : 0.0f;

    // ---- phase A: hbf = acc2[0..3]*dn via LDS -> coalesced uint2 (bf16; k_hcvt1 -> fp8) ----
    #pragma unroll
    for (int t = 0; t < 4; ++t)
        #pragma unroll
        for (int reg = 0; reg < 4; ++reg)
            st[w][q * 4 + reg][t * 16 + ql] = f2bf(acc2[t][reg] * dn[reg]);
    #pragma unroll
    for (int it = 0; it < 4; ++it) {
        int i = it * 64 + lane;
        int r = i >> 4, c8 = i & 15;
        int n = rowBase + r;
        uint2 v = *reinterpret_cast<const uint2*>(&st[w][r][c8 * 4]);
        if (n < NUM_NODES)
            *reinterpret_cast<uint2*>(&hbf[(size_t)n * DIM_ID + c8 * 4]) = v;
    }

    // ---- phase B: xhat2 = lrelu(acc2[4..7]+lb1) (+idemb coalesced) ----
    #pragma unroll
    for (int t = 0; t < 4; ++t) {
        int colg = t * 16 + ql;
        float lbl = lb1[colg];
        #pragma unroll
        for (int reg = 0; reg < 4; ++reg)
            st[w][q * 4 + reg][colg] = f2bf(lrelu(acc2[4 + t][reg] + lbl));
    }
    #pragma unroll
    for (int it = 0; it < 4; ++it) {
        int i = it * 64 + lane;
        int r = i >> 4, c8 = i & 15;
        int n = rowBase + r;
        if (n < NUM_NODES) {
            uint2 s = *reinterpret_cast<const uint2*>(&st[w][r][c8 * 4]);
            float4 idv = *reinterpret_cast<const float4*>(&idemb[(size_t)n * DIM_ID + c8 * 4]);
            uint2 o;
            o.x = (unsigned)f2bf(bflo(s.x) + idv.x) | ((unsigned)f2bf(bfhi(s.x) + idv.y) << 16);
            o.y = (unsigned)f2bf(bflo(s.y) + idv.z) | ((unsigned)f2bf(bfhi(s.y) + idv.w) << 16);
            *reinterpret_cast<uint2*>(&xhat2[(size_t)n * DIM_ID + c8 * 4]) = o;
        }
    }
}

// ---------------- final (MFMA): out = lrelu(lrelu(H2)@gw1 + gb1 + xhat2) ----------------
__global__ void __launch_bounds__(256, 3) k_final(
    const unsigned short* __restrict__ Hb, const unsigned short* __restrict__ xhat,
    const unsigned short* __restrict__ wf64,
    const float* __restrict__ gb, float* __restrict__ out)
{
    const int lane = threadIdx.x & 63;
    const int w = threadIdx.x >> 6;
    const int ql = lane & 15, q = lane >> 4;
    const int rowBase = (blockIdx.x * 4 + w) * 16;
    const int rowc = min(rowBase + ql, NUM_NODES - 1);

    bf8_t ha[2];
    #pragma unroll
    for (int ks = 0; ks < 2; ++ks) {
        uint4 u = *reinterpret_cast<const uint4*>(&Hb[(size_t)rowc * DIM_ID + ks * 32 + q * 8]);
        bf8_t a;
        a[0] = (short)f2bf(lrelu(bflo(u.x))); a[1] = (short)f2bf(lrelu(bfhi(u.x)));
        a[2] = (short)f2bf(lrelu(bflo(u.y))); a[3] = (short)f2bf(lrelu(bfhi(u.y)));
        a[4] = (short)f2bf(lrelu(bflo(u.z))); a[5] = (short)f2bf(lrelu(bfhi(u.z)));
        a[6] = (short)f2bf(lrelu(bflo(u.w))); a[7] = (short)f2bf(lrelu(bfhi(u.w)));
        ha[ks] = a;
    }

    const bf8_t* gw1f = reinterpret_cast<const bf8_t*>(wf64 + 1536 * 8);
    f4_t acc[4];
    #pragma unroll
    for (int t = 0; t < 4; ++t) acc[t] = (f4_t){0.f, 0.f, 0.f, 0.f};
    #pragma unroll
    for (int ks = 0; ks < 2; ++ks)
        #pragma unroll
        for (int t = 0; t < 4; ++t)
            acc[t] = __builtin_amdgcn_mfma_f32_16x16x32_bf16(ha[ks], gw1f[(ks * 4 + t) * 64 + lane], acc[t], 0, 0, 0);

    int nn[4];
    #pragma unroll
    for (int reg = 0; reg < 4; ++reg) nn[reg] = rowBase + q * 4 + reg;

    #pragma unroll
    for (int t = 0; t < 4; ++t) {
        int colg = t * 16 + ql;
        float gbl = gb[colg];
        #pragma unroll
        for (int reg = 0; reg < 4; ++reg)
            if (nn[reg] < NUM_NODES) {
                size_t o = (size_t)nn[reg] * DIM_ID + colg;
                out[o] = lrelu(acc[t][reg] + gbl + bf2f(xhat[o]));
            }
    }
}

extern "C" void kernel_launch(void* const* d_in, const int* in_sizes, int n_in,
                              void* d_out, int out_size, void* d_ws, size_t ws_size,
                              hipStream_t stream)
{
    const float* features = (const float*)d_in[0];
    const float* idemb    = (const float*)d_in[1];
    const float* pref     = (const float*)d_in[2];
    const float* Wg0      = (const float*)d_in[3];
    const float* Wg1      = (const float*)d_in[4];
    const float* lw0      = (const float*)d_in[5];
    const float* lb0      = (const float*)d_in[6];
    const float* lw1      = (const float*)d_in[7];
    const float* lb1      = (const float*)d_in[8];
    const float* gw0      = (const float*)d_in[9];
    const float* gb0      = (const float*)d_in[10];
    const float* gw1      = (const float*)d_in[11];
    const float* gb1      = (const float*)d_in[12];
    const int*   edges    = (const int*)d_in[13];
    const int*   row      = edges;
    const int*   col      = edges + NUM_EDGES;

    char* ws = (char*)d_ws;
    int*      hist  = (int*)(ws + 0);             // 384,160 B (pad 512K)
    int*      bcnt  = (int*)(ws + 524288);        // 4 KB
    int*      boff  = (int*)(ws + 528384);        // 4 KB
    int*      offs  = (int*)(ws + 532480);        // 512K
    int*      cnt   = (int*)(ws + 1056768);       // 512K
    float*    dis   = (float*)(ws + 1581056);     // 512K
    unsigned short* wfrag = (unsigned short*)(ws + 2105344);   // 64 KB (layer-1 table)
    unsigned short* wf64  = (unsigned short*)(ws + 2170880);   // 32 KB (gw0|Wg1|lw1|gw1)
    unsigned short* xn    = (unsigned short*)(ws + 2236416);   // 51.2 MB (dead after k_l1)
    //   aliases within xn region (all born after k_l1 completes):
    int*      ecol  = (int*)(ws + 2236416);                    // 8 MB
    unsigned* epack = (unsigned*)(ws + 10625024);              // 8 MB
    unsigned short* Hbf   = (unsigned short*)(ws + 19013632);  // 12.8 MB (ends 31.8 MB)
    unsigned char*  hbf8  = (unsigned char*)(ws + 32000000);   // 6.4 MB fp8 table (ends 38.4 MB < 53.4)
    unsigned short* hbf   = (unsigned short*)(ws + 53436416);  // 12.8 MB (bf16, pre-cvt)
    unsigned short* xhatb = (unsigned short*)(ws + 66236416);  // 12.8 MB -> 79.0 MB total
    float* out   = (float*)d_out;

    const int l1Blocks = (NUM_NODES + 63) / 64;     // 1563
    const int gatherBlocks = NUM_NODES / 4;         // 25000
    const int cvtBlocks = NUM_NODES * 16 / 256;     // 6250

    // ---- weight prep + normalize + bucket histogram/scan ----
    k_wprep<<<16, 256, 0, stream>>>(Wg0, lw0, wfrag);
    k_wprep64<<<8, 256, 0, stream>>>(gw0, Wg1, lw1, gw1, wf64);
    k_xnorm<<<NUM_NODES / 4, 256, 0, stream>>>(pref, features, xn);
    k_hist<<<NCHUNK, 256, 0, stream>>>(row, hist);
    k_off1<<<NBUCKET, 256, 0, stream>>>(hist, bcnt);
    k_bscan<<<1, 512, 0, stream>>>(bcnt, boff);

    // ---- layer 1 GEMM (before CSR so xn region can be recycled) ----
    k_l1<<<l1Blocks, 256, 0, stream>>>(xn, wfrag, lb0, idemb, hbf, xhatb);

    // ---- CSR build into recycled xn region ----
    k_bin2<<<NCHUNK, 256, 0, stream>>>(row, col, hist, boff, epack);
    k_csr<<<NBUCKET, 512, 0, stream>>>(epack, boff, offs, cnt, dis, ecol);
    k_hcvt<<<cvtBlocks, 256, 0, stream>>>((const uint2*)hbf, dis, (unsigned*)hbf8);

    // ---- layer 1 aggregate ----
    k_gather<<<gatherBlocks, 256, 0, stream>>>(hbf8, dis, offs, cnt, ecol, Hbf);

    // ---- combine1 + layer2 pre (fused, MFMA) ----
    k_mid<<<l1Blocks, 256, 0, stream>>>(Hbf, xhatb, wf64, gb0, lb1, idemb, dis,
                                        hbf, xhatb);
    k_hcvt1<<<cvtBlocks, 256, 0, stream>>>((const uint2*)hbf, (unsigned*)hbf8);

    // ---- layer 2 aggregate + final combine (MFMA) ----
    k_gather<<<gatherBlocks, 256, 0, stream>>>(hbf8, dis, offs, cnt, ecol, Hbf);
    k_final<<<l1Blocks, 256, 0, stream>>>(Hbf, xhatb, wf64, gb1, out);
}